// Round 9
// baseline (21.605 us; speedup 1.0000x reference)
//
#include <hip/hip_runtime.h>
#include <math.h>
#include <stdint.h>

#define HF 64
#define WF 64
#define CC 512
#define NROI 256
#define NBINS 21   // 1 + 4 + 16

__device__ __forceinline__ float4 max4(float4 a, float4 b) {
    float4 r;
    r.x = fmaxf(a.x, b.x); r.y = fmaxf(a.y, b.y);
    r.z = fmaxf(a.z, b.z); r.w = fmaxf(a.w, b.w);
    return r;
}

__device__ __forceinline__ float4 ld4(const float* __restrict__ p, uint32_t byteoff) {
    return *(const float4*)((const char*)p + byteoff);
}

// ---------------- P1: x-direction max pyramids ----------------
// Mx1[y][x][c] = max(img[y][x], img[y][x+1])        (x clamped to 63)
// Mx2[y][x][c] = max over img[y][x..x+3]            (clamped)
// Same [y][x][c] layout as img; i (float4 index) == y*8192 + x*128 + c4.
__global__ __launch_bounds__(256) void build_xpyr(
    const float* __restrict__ img,
    float* __restrict__ mx1,
    float* __restrict__ mx2)
{
    const uint32_t i  = blockIdx.x * 256 + threadIdx.x;   // [0, 524288)
    const uint32_t c4 = i & 127;
    const uint32_t x  = (i >> 7) & 63;
    const uint32_t y  = i >> 13;
    const uint32_t rowb = y * (64 * 128);

    const float4* imgv = (const float4*)img;
    const uint32_t x1 = min(x + 1, 63u);
    const uint32_t x2 = min(x + 2, 63u);
    const uint32_t x3 = min(x + 3, 63u);

    const float4 v0 = imgv[rowb + x  * 128 + c4];
    const float4 v1 = imgv[rowb + x1 * 128 + c4];
    const float4 v2 = imgv[rowb + x2 * 128 + c4];
    const float4 v3 = imgv[rowb + x3 * 128 + c4];

    const float4 m1 = max4(v0, v1);
    const float4 m2 = max4(m1, max4(v2, v3));
    ((float4*)mx1)[i] = m1;
    ((float4*)mx2)[i] = m2;
}

// ---------------- P2: query kernel (RMQ lookups) ----------------
// block = (roi, channel-quarter of 128 ch), 512 threads = 8 waves.
// wave wv: jy = wv>>1, rp = wv&1 (row parity). Per (row, jx): ONE wave-load —
// lanes 0-31 read window at xa=x1, lanes 32-63 at xb=x2-2^k (same 128-ch
// quarter); k=1 (Mx1) for len 2-3, k=2 (Mx2) for len 4-8. Overlapping
// power-of-2 windows cover [x1,x2) exactly; max is idempotent -> bitwise exact.
// p4 = shfl(32) + rp-pair LDS combine; p2/p1 hierarchical (exact, proven r0).
// XCD swizzle (proven r2-r8): quarter q=(bid&7)>>1 -> XCD pair {2q,2q+1}.
__global__ __launch_bounds__(512) void roi_pool_query(
    const float* __restrict__ mx1,
    const float* __restrict__ mx2,
    const float* __restrict__ rois,
    float* __restrict__ out)
{
    __shared__ float ldsA[4][2][4][128];   // [jy][rp][jx][ch]
    __shared__ float ldsB[4][4][128];      // [jy][jx][ch]
    __shared__ float ldsC[2][2][128];      // [i2][j2][ch]

    const int bid  = blockIdx.x;                    // [0, 1024)
    const int q    = (bid & 7) >> 1;
    const int roi  = ((bid >> 3) << 1) | (bid & 1); // [0, 256) bijective
    const int tid  = threadIdx.x;
    const int wv   = tid >> 6;                      // 0..7
    const int jy   = wv >> 1;
    const int rp   = wv & 1;
    const int lane = tid & 63;
    const int half = lane >> 5;                     // window A/B select
    const int cl   = lane & 31;
    const int c0   = q * 128 + cl * 4;

    const float x = rois[roi * 4 + 0];
    const float y = rois[roi * 4 + 1];
    const float w = rois[roi * 4 + 2];
    const float h = rois[roi * 4 + 3];

    // Reference quirk: x-boundaries (W axis) use col_len = h/p; y-boundaries use w/p.
    const float clh = h * 0.25f;   // exact
    const float clw = w * 0.25f;   // exact

    int bx[5];
#pragma unroll
    for (int i = 0; i < 5; ++i)
        bx[i] = (int)rintf(__fadd_rn(x, __fmul_rn((float)i, clh)));

    const int y1 = (int)rintf(__fadd_rn(y, __fmul_rn((float)jy,       clw)));
    const int y2 = (int)rintf(__fadd_rn(y, __fmul_rn((float)(jy + 1), clw)));

    const uint32_t ROWB = WF * CC * 4;   // 131072
    const uint32_t PXB  = CC * 4;        // 2048
    const uint32_t cb   = (uint32_t)c0 * 4;

    // per-jx: pyramid select + column for this lane-half (wave-uniform per jx)
    const float* base[4];
    uint32_t coloff[4];
#pragma unroll
    for (int jx = 0; jx < 4; ++jx) {
        const int len = bx[jx + 1] - bx[jx];        // in [2, 8]
        const int big = (len >= 4);
        base[jx] = big ? mx2 : mx1;
        const int xa = bx[jx];
        const int xb = bx[jx + 1] - (big ? 4 : 2);
        coloff[jx] = (uint32_t)(half ? xb : xa) * PXB + cb;
    }

    float4 acc[4];
#pragma unroll
    for (int jx = 0; jx < 4; ++jx) {
        acc[jx].x = -INFINITY; acc[jx].y = -INFINITY;
        acc[jx].z = -INFINITY; acc[jx].w = -INFINITY;
    }

    for (int r = y1 + rp; r < y2; r += 2) {
        const uint32_t ro = (uint32_t)r * ROWB;
        acc[0] = max4(acc[0], ld4(base[0], ro + coloff[0]));
        acc[1] = max4(acc[1], ld4(base[1], ro + coloff[1]));
        acc[2] = max4(acc[2], ld4(base[2], ro + coloff[2]));
        acc[3] = max4(acc[3], ld4(base[3], ro + coloff[3]));
    }

    // combine window halves
#pragma unroll
    for (int jx = 0; jx < 4; ++jx) {
        float4 a = acc[jx];
        a.x = fmaxf(a.x, __shfl_xor(a.x, 32));
        a.y = fmaxf(a.y, __shfl_xor(a.y, 32));
        a.z = fmaxf(a.z, __shfl_xor(a.z, 32));
        a.w = fmaxf(a.w, __shfl_xor(a.w, 32));
        acc[jx] = a;
    }

    if (half == 0) {
#pragma unroll
        for (int jx = 0; jx < 4; ++jx)
            *(float4*)(&ldsA[jy][rp][jx][cl * 4]) = acc[jx];
    }
    __syncthreads();

    float* outr = out + (size_t)roi * (NBINS * CC) + c0;

    // p4: row-parity combine
    if (rp == 0 && half == 0) {
#pragma unroll
        for (int jx = 0; jx < 4; ++jx) {
            const float4 m = max4(*(const float4*)(&ldsA[jy][0][jx][cl * 4]),
                                  *(const float4*)(&ldsA[jy][1][jx][cl * 4]));
            *(float4*)(outr + (size_t)(5 + jx * 4 + jy) * CC) = m;
            *(float4*)(&ldsB[jy][jx][cl * 4]) = m;
        }
    }
    __syncthreads();

    // p2
    if (wv < 4 && half == 0) {
        const int i2 = wv >> 1;
        const int j2 = wv & 1;
        const float4 f00 = *(const float4*)(&ldsB[2*j2  ][2*i2  ][cl * 4]);
        const float4 f01 = *(const float4*)(&ldsB[2*j2  ][2*i2+1][cl * 4]);
        const float4 f10 = *(const float4*)(&ldsB[2*j2+1][2*i2  ][cl * 4]);
        const float4 f11 = *(const float4*)(&ldsB[2*j2+1][2*i2+1][cl * 4]);
        const float4 a = max4(max4(f00, f01), max4(f10, f11));
        *(float4*)(outr + (size_t)(1 + i2 * 2 + j2) * CC) = a;
        *(float4*)(&ldsC[i2][j2][cl * 4]) = a;
    }
    __syncthreads();

    // p1
    if (wv == 0 && half == 0) {
        const float4 a00 = *(const float4*)(&ldsC[0][0][cl * 4]);
        const float4 a01 = *(const float4*)(&ldsC[0][1][cl * 4]);
        const float4 a10 = *(const float4*)(&ldsC[1][0][cl * 4]);
        const float4 a11 = *(const float4*)(&ldsC[1][1][cl * 4]);
        *(float4*)(outr) = max4(max4(a00, a01), max4(a10, a11));
    }
}

// ---------------- Fallback (round-7 kernel, proven 21.5 us) ----------------
__global__ __launch_bounds__(512) void roi_pool_fused_fb(
    const float* __restrict__ img,
    const float* __restrict__ rois,
    float* __restrict__ out)
{
    __shared__ float ldsA[4][2][4][128];
    __shared__ float ldsB[4][4][128];
    __shared__ float ldsC[2][2][128];

    const int bid  = blockIdx.x;
    const int q    = (bid & 7) >> 1;
    const int roi  = ((bid >> 3) << 1) | (bid & 1);
    const int tid  = threadIdx.x;
    const int wv   = tid >> 6;
    const int jy   = wv >> 1;
    const int rp   = wv & 1;
    const int lane = tid & 63;
    const int half = lane >> 5;
    const int cl   = lane & 31;
    const int c0   = q * 128 + cl * 4;

    const float x = rois[roi * 4 + 0];
    const float y = rois[roi * 4 + 1];
    const float w = rois[roi * 4 + 2];
    const float h = rois[roi * 4 + 3];
    const float clh = h * 0.25f;
    const float clw = w * 0.25f;

    int bx[5];
#pragma unroll
    for (int i = 0; i < 5; ++i)
        bx[i] = (int)rintf(__fadd_rn(x, __fmul_rn((float)i, clh)));

    const int y1 = (int)rintf(__fadd_rn(y, __fmul_rn((float)jy,       clw)));
    const int y2 = (int)rintf(__fadd_rn(y, __fmul_rn((float)(jy + 1), clw)));

    const int w01 = max(bx[1] - bx[0], bx[2] - bx[1]);
    const int w23 = max(bx[3] - bx[2], bx[4] - bx[3]);
    const int K   = (max(w01, w23) + 1) >> 1;

    float4 acc[4];
#pragma unroll
    for (int jx = 0; jx < 4; ++jx) {
        acc[jx].x = -INFINITY; acc[jx].y = -INFINITY;
        acc[jx].z = -INFINITY; acc[jx].w = -INFINITY;
    }

    const uint32_t ROWB = WF * CC * 4;
    const uint32_t PXB  = CC * 4;
    const uint32_t cb   = (uint32_t)c0 * 4;

    for (int r = y1 + rp; r < y2; r += 2) {
        const uint32_t ro = cb + (uint32_t)r * ROWB;
        for (int k = 0; k < K; ++k) {
            const int cc2 = 2 * k + half;
#pragma unroll
            for (int jx = 0; jx < 4; ++jx) {
                const int col = min(bx[jx] + cc2, bx[jx + 1] - 1);
                acc[jx] = max4(acc[jx], ld4(img, ro + (uint32_t)col * PXB));
            }
        }
    }

#pragma unroll
    for (int jx = 0; jx < 4; ++jx) {
        float4 a = acc[jx];
        a.x = fmaxf(a.x, __shfl_xor(a.x, 32));
        a.y = fmaxf(a.y, __shfl_xor(a.y, 32));
        a.z = fmaxf(a.z, __shfl_xor(a.z, 32));
        a.w = fmaxf(a.w, __shfl_xor(a.w, 32));
        acc[jx] = a;
    }

    if (half == 0) {
#pragma unroll
        for (int jx = 0; jx < 4; ++jx)
            *(float4*)(&ldsA[jy][rp][jx][cl * 4]) = acc[jx];
    }
    __syncthreads();

    float* outr = out + (size_t)roi * (NBINS * CC) + c0;

    if (rp == 0 && half == 0) {
#pragma unroll
        for (int jx = 0; jx < 4; ++jx) {
            const float4 m = max4(*(const float4*)(&ldsA[jy][0][jx][cl * 4]),
                                  *(const float4*)(&ldsA[jy][1][jx][cl * 4]));
            *(float4*)(outr + (size_t)(5 + jx * 4 + jy) * CC) = m;
            *(float4*)(&ldsB[jy][jx][cl * 4]) = m;
        }
    }
    __syncthreads();

    if (wv < 4 && half == 0) {
        const int i2 = wv >> 1;
        const int j2 = wv & 1;
        const float4 f00 = *(const float4*)(&ldsB[2*j2  ][2*i2  ][cl * 4]);
        const float4 f01 = *(const float4*)(&ldsB[2*j2  ][2*i2+1][cl * 4]);
        const float4 f10 = *(const float4*)(&ldsB[2*j2+1][2*i2  ][cl * 4]);
        const float4 f11 = *(const float4*)(&ldsB[2*j2+1][2*i2+1][cl * 4]);
        const float4 a = max4(max4(f00, f01), max4(f10, f11));
        *(float4*)(outr + (size_t)(1 + i2 * 2 + j2) * CC) = a;
        *(float4*)(&ldsC[i2][j2][cl * 4]) = a;
    }
    __syncthreads();

    if (wv == 0 && half == 0) {
        const float4 a00 = *(const float4*)(&ldsC[0][0][cl * 4]);
        const float4 a01 = *(const float4*)(&ldsC[0][1][cl * 4]);
        const float4 a10 = *(const float4*)(&ldsC[1][0][cl * 4]);
        const float4 a11 = *(const float4*)(&ldsC[1][1][cl * 4]);
        *(float4*)(outr) = max4(max4(a00, a01), max4(a10, a11));
    }
}

extern "C" void kernel_launch(void* const* d_in, const int* in_sizes, int n_in,
                              void* d_out, int out_size, void* d_ws, size_t ws_size,
                              hipStream_t stream) {
    const float* img  = (const float*)d_in[0];   // (1,64,64,512) fp32
    const float* rois = (const float*)d_in[1];   // (1,256,4) fp32
    float* out = (float*)d_out;                  // (1,256,21*512) fp32

    const size_t PYR = (size_t)HF * WF * CC;     // 2M floats = 8 MB

    if (ws_size >= 2 * PYR * sizeof(float)) {
        float* mx1 = (float*)d_ws;
        float* mx2 = mx1 + PYR;
        build_xpyr<<<dim3(2048), dim3(256), 0, stream>>>(img, mx1, mx2);
        roi_pool_query<<<dim3(NROI * 4), dim3(512), 0, stream>>>(mx1, mx2, rois, out);
    } else {
        roi_pool_fused_fb<<<dim3(NROI * 4), dim3(512), 0, stream>>>(img, rois, out);
    }
}